// Round 9
// baseline (168.060 us; speedup 1.0000x reference)
//
#include <hip/hip_runtime.h>
#include <hip/hip_bf16.h>

// Problem constants
#define BATCH 2
#define SEQ   2048
#define DMODEL 1024
#define NHEADS 16
#define DHEAD  64
#define MTOT   (BATCH * SEQ)         // 4096 rows
#define QKSTR  2048                  // q,k buffer row stride (v stored separately)

typedef __attribute__((ext_vector_type(8))) short bf16x8;   // 8 bf16 in 4 VGPRs
typedef __attribute__((ext_vector_type(4))) short bf16x4;   // 4 bf16 in 2 VGPRs
typedef __attribute__((ext_vector_type(4))) float f32x4;

// 16B async global->LDS copy (LDS dest = wave-uniform base + lane*16).
__device__ __forceinline__ void glds16(const void* g, void* l)
{
    __builtin_amdgcn_global_load_lds(
        (const __attribute__((address_space(1))) unsigned int*)g,
        (__attribute__((address_space(3))) unsigned int*)l, 16, 0, 0);
}

// v_cvt_pk_bf16_f32: dst.lo = bf16(lo), dst.hi = bf16(hi). No builtin (m240).
__device__ __forceinline__ unsigned cvt_pk_bf16(float lo, float hi)
{
    unsigned r;
    asm("v_cvt_pk_bf16_f32 %0, %1, %2" : "=v"(r) : "v"(lo), "v"(hi));
    return r;
}

// raw v_exp_f32 (2^x) - skips libm range/denormal fixup; |x| < 16 here.
__device__ __forceinline__ float fast_exp2(float x)
{
    float r;
    asm("v_exp_f32 %0, %1" : "=v"(r) : "v"(x));
    return r;
}

// ---------------------------------------------------------------------------
// fused fp32 -> bf16 casts (x, qkv_w, proj_w in one launch)
// ---------------------------------------------------------------------------
__global__ void cast_all_kernel(
    const float* __restrict__ a, __hip_bfloat16* __restrict__ oa, int na4,
    const float* __restrict__ b, __hip_bfloat16* __restrict__ ob, int nb4,
    const float* __restrict__ c, __hip_bfloat16* __restrict__ oc, int nc4)
{
    int i = blockIdx.x * blockDim.x + threadIdx.x;
    const float* src; __hip_bfloat16* dst; int j = i;
    if (j < na4) { src = a; dst = oa; }
    else {
        j -= na4;
        if (j < nb4) { src = b; dst = ob; }
        else {
            j -= nb4;
            if (j >= nc4) return;
            src = c; dst = oc;
        }
    }
    float4 v = ((const float4*)src)[j];
    __hip_bfloat16 tmp[4];
    tmp[0] = __float2bfloat16(v.x);
    tmp[1] = __float2bfloat16(v.y);
    tmp[2] = __float2bfloat16(v.z);
    tmp[3] = __float2bfloat16(v.w);
    *(uint2*)(dst + 4 * (size_t)j) = *(const uint2*)tmp;
}

// ---------------------------------------------------------------------------
// GEMM: out[M,N] = A[M,K] @ W[N,K]^T + bias[N]; bf16 in, fp32 acc.
// TMxTN tile (template), BK=64, global_load_lds(16B) staging, XOR-swizzled
// LDS (chunk ^ (row&7), 64-el rows -> conflict-free). 4 waves in 2x2 grid.
// qkv: 128x128 (768 blocks = 3/CU); proj: 64x128 (512 blocks = 2/CU).
// MODE 0: plain store (stride N). MODE 1 (qkv): cols<2048 RoPE pairs into qk
// buffer (stride QKSTR); cols>=2048 V transposed to vtg[(b,h),dh,s].
// ---------------------------------------------------------------------------
#define GBK 64

__device__ __forceinline__ void store_out(float* p, float v) { *p = v; }
__device__ __forceinline__ void store_out(__hip_bfloat16* p, float v) { *p = __float2bfloat16(v); }

template <typename OutT, int MODE, int TM, int TN, int MINW>
__global__ __launch_bounds__(256, MINW) void gemm_bias_kernel(
    const __hip_bfloat16* __restrict__ A, const __hip_bfloat16* __restrict__ W,
    const float* __restrict__ bias, OutT* __restrict__ out,
    __hip_bfloat16* __restrict__ vtg,
    int M, int N, int K)
{
    const int MI = TM / 32;                    // m-frags per wave
    const int NI = TN / 32;                    // n-frags per wave
    const int bm = blockIdx.x * TM;
    const int bn = blockIdx.y * TN;
    const int tid = threadIdx.x;
    const int wave = tid >> 6;
    const int lane = tid & 63;
    const int quad = lane >> 4;
    const int l16 = lane & 15;
    const int wm = (wave & 1) * (TM / 2);
    const int wn = (wave >> 1) * (TN / 2);

    __shared__ __hip_bfloat16 As[TM * GBK];    // TM/64 * 8 KB
    __shared__ __hip_bfloat16 Bs[TN * GBK];    // TN/64 * 8 KB

    f32x4 acc[MI][NI] = {};

    const int srow = lane >> 3;
    const int gc8 = (((lane & 7) ^ srow)) * 8;

    for (int kt = 0; kt < K; kt += GBK) {
#pragma unroll
        for (int t = 0; t < MI; t++) {         // A: TM/8 chunks of 8 rows, MI/wave
            int i = wave * MI + t;
            glds16(A + (size_t)(bm + i * 8 + srow) * K + kt + gc8, As + i * 512);
        }
#pragma unroll
        for (int t = 0; t < NI; t++) {         // B: TN/8 chunks, NI/wave
            int i = wave * NI + t;
            glds16(W + (size_t)(bn + i * 8 + srow) * K + kt + gc8, Bs + i * 512);
        }
        __syncthreads();

#pragma unroll
        for (int kk = 0; kk < 2; kk++) {
            bf16x8 af[MI], bfr[NI];
#pragma unroll
            for (int i = 0; i < MI; i++) {
                int ra = wm + i * 16 + l16;
                af[i] = *(const bf16x8*)(As + ra * 64 + (((kk << 2) + quad) ^ (ra & 7)) * 8);
            }
#pragma unroll
            for (int i = 0; i < NI; i++) {
                int rb = wn + i * 16 + l16;
                bfr[i] = *(const bf16x8*)(Bs + rb * 64 + (((kk << 2) + quad) ^ (rb & 7)) * 8);
            }
#pragma unroll
            for (int mi = 0; mi < MI; mi++)
#pragma unroll
                for (int ni = 0; ni < NI; ni++)
                    acc[mi][ni] = __builtin_amdgcn_mfma_f32_16x16x32_bf16(
                        af[mi], bfr[ni], acc[mi][ni], 0, 0, 0);
        }
        __syncthreads();
    }

    if (MODE == 1 && (bn + wn) < 2 * DMODEL) {
        // q/k columns: RoPE pairs (dh, dh+32) = (acc[.][ni], acc[.][ni+2]).
#pragma unroll
        for (int ni = 0; ni < 2; ni++) {
            int col = bn + wn + ni * 16 + l16;
            int i32 = col & 31;
            float invf = exp2f(-13.287712379549449f * (float)i32 * (1.0f / 32.0f));
            float b1 = bias[col], b2 = bias[col + 32];
#pragma unroll
            for (int mi = 0; mi < MI; mi++) {
#pragma unroll
                for (int r = 0; r < 4; r++) {
                    int row = bm + wm + mi * 16 + quad * 4 + r;
                    int s = row & (SEQ - 1);
                    float ang = (float)s * invf;
                    float sn, cs;
                    __sincosf(ang, &sn, &cs);
                    float x1 = acc[mi][ni][r] + b1;
                    float x2 = acc[mi][ni + 2][r] + b2;
                    store_out(&out[(size_t)row * QKSTR + col], x1 * cs - x2 * sn);
                    store_out(&out[(size_t)row * QKSTR + col + 32], x2 * cs + x1 * sn);
                }
            }
        }
    } else if (MODE == 1) {
        // V columns: write transposed into vtg[(b*16+h)*64 + dh][s], 8B packed
#pragma unroll
        for (int ni = 0; ni < NI; ni++) {
            int colg = bn + wn + ni * 16 + l16;
            int vcol = colg - 2 * DMODEL;
            int hh = vcol >> 6, dh = vcol & 63;
            float bv = bias[colg];
#pragma unroll
            for (int mi = 0; mi < MI; mi++) {
                int row0 = bm + wm + mi * 16 + quad * 4;
                int bb = row0 >> 11;
                int ss = row0 & (SEQ - 1);
                __hip_bfloat16 tmp[4];
#pragma unroll
                for (int r = 0; r < 4; r++)
                    tmp[r] = __float2bfloat16(acc[mi][ni][r] + bv);
                *(uint2*)(vtg + (((size_t)bb * NHEADS + hh) * DHEAD + dh) * SEQ + ss) =
                    *(uint2*)tmp;
            }
        }
    } else {
#pragma unroll
        for (int mi = 0; mi < MI; mi++)
#pragma unroll
            for (int ni = 0; ni < NI; ni++) {
                int col = bn + wn + ni * 16 + l16;
                float bv = bias[col];
#pragma unroll
                for (int r = 0; r < 4; r++) {
                    int row = bm + wm + mi * 16 + quad * 4 + r;
                    store_out(&out[(size_t)row * N + col], acc[mi][ni][r] + bv);
                }
            }
    }
}

// ---------------------------------------------------------------------------
// MFMA flash attention v12: QBLK=128 - halve the staged K/V bytes.
// MODEL (fits v6-v11): flash is staging-bandwidth-bound. Staged bytes =
// 16896 tiles x 16KB = 270MB at ~10.4 B/cy/CU (6.4 TB/s) = 43us; every
// scheduling/occupancy/LDS variant moved the same bytes -> same 42-45us.
// v12: q-block = 128 rows -> K/V re-reads halve: 139MB -> ~22us.
// Structure: 512 blocks x 8 waves (512 thr). Wave = (kw = w&3: keys
// [kw*16,+16), qg = w>>2: q rows [qg*64,+64) = 4 tiles). Per-wave body is
// v11's verified one (8 QK 16x16x32, in-register P via cvt_pk = 16x16x16
// A-frag, 16+4 PV, ones-col l). Ring-3 K/V (48KB) + counted vmcnt(2).
// VGPR ~170 -> 1 block/CU; fine under BW-bound (per-CU demand halves).
// Grid: LPT map qt2 = 15-(idx>>5), bh = idx&31 (longest first, bh%8 XCD
// affinity kept). Per-wave diag tile jd = 2*qt2+qg; qg=0 skips last tile.
// Epilogue: 4-way k-slice reduction via LDS reuse (4 dt passes, 34KB).
// ---------------------------------------------------------------------------
__global__ __launch_bounds__(512, 2) void flash_attn_mfma_kernel(
    const __hip_bfloat16* __restrict__ qkb,
    const __hip_bfloat16* __restrict__ vtg,
    __hip_bfloat16* __restrict__ ctx)
{
    const int idx = blockIdx.x;
    const int bh = idx & 31;
    const int qt2 = 15 - (idx >> 5);        // LPT: longest first
    const int b = bh >> 4, h = bh & 15;
    const int tid = threadIdx.x;
    const int w = tid >> 6;                 // 0..7
    const int lane = tid & 63;
    const int quad = lane >> 4;
    const int l16 = lane & 15;
    const int kw = w & 3;                   // key slice [kw*16, +16) of tile
    const int qg = w >> 2;                  // q half [qg*64, +64)

    // 48 KB: K ring3 (3x4096 el) | V ring3 (3x4096 el); epilogue reuses it.
    __shared__ alignas(16) __hip_bfloat16 smem[24576];
    __hip_bfloat16* const ksb = smem;
    __hip_bfloat16* const vtb = smem + 12288;

    const __hip_bfloat16* qbase = qkb + (size_t)b * SEQ * QKSTR + h * DHEAD;
    const __hip_bfloat16* kbase = qbase + DMODEL;
    const __hip_bfloat16* vbase = vtg + (size_t)bh * DHEAD * SEQ;

    // Q B-frags for this wave's 4 q-tiles (B[k=kk*32+quad*8+j][n=l16])
    bf16x8 qf[4][2];
#pragma unroll
    for (int tq = 0; tq < 4; tq++) {
        const __hip_bfloat16* qr =
            qbase + (size_t)(qt2 * 128 + qg * 64 + tq * 16 + l16) * QKSTR;
        qf[tq][0] = *(const bf16x8*)(qr + quad * 8);
        qf[tq][1] = *(const bf16x8*)(qr + 32 + quad * 8);
    }

    // staging: wave w stages rows [w*8, w*8+8) of K tile and of Vt tile
    const int srow = lane >> 3;
    const int gc8 = ((lane & 7) ^ srow) * 8;          // XOR swizzle, matches readers
    const __hip_bfloat16* kg = kbase + (size_t)(w * 8 + srow) * QKSTR + gc8;
    const __hip_bfloat16* vg = vbase + (size_t)(w * 8 + srow) * SEQ + gc8;

    // hoisted LDS offsets (loop-invariant, element units)
    const int xr = l16 & 7;
    // K A-frag (16x16x32): row kw*16+l16, chunk (kk*4+quad)^xr
    const int foK0 = (kw * 16 + l16) * 64 + ((quad ^ xr) << 3);
    const int foK1 = (kw * 16 + l16) * 64 + (((4 + quad) ^ xr) << 3);
    // V B-frag (16x16x16, b64): row dt*16+l16, keys kw*16+quad*4..+3
    int vb[4];
#pragma unroll
    for (int dt = 0; dt < 4; dt++)
        vb[dt] = (dt * 16 + l16) * 64 +
                 ((((kw << 1) + (quad >> 1)) ^ xr) << 3) + ((quad & 1) << 2);

    const short ov = (l16 == 0) ? (short)0x3F80 : (short)0;
    const bf16x4 ones4 = {ov, ov, ov, ov};

    f32x4 oacc[4][4] = {};   // O[tq][dt]: q=tq*16+quad*4+r, dh=dt*16+l16
    f32x4 lacc[4] = {};      // l[tq] via ones-col MFMA (valid at l16==0)

    auto stage = [&](int t, int buf) {
        glds16(kg + (size_t)t * 64 * QKSTR, ksb + buf * 4096 + w * 512);
        glds16(vg + t * 64,                 vtb + buf * 4096 + w * 512);
    };

    const int nit = 2 * qt2 + 2;            // k-tiles for this q-block
    const int jd = 2 * qt2 + qg;            // this wave's diagonal tile

    // prologue: 2-deep prefetch (tile 1 always memory-valid: nit >= 2)
    stage(0, 0);
    stage(1, 1);

    int cur = 0;                            // jt % 3
    for (int jt = 0; jt < nit; jt++) {
        // counted wait: tile jt's 2 loads landed; tile jt+1's stay in flight
        if (jt < nit - 1) asm volatile("s_waitcnt vmcnt(2)" ::: "memory");
        else              asm volatile("s_waitcnt vmcnt(0)" ::: "memory");
        __builtin_amdgcn_s_barrier();
        __builtin_amdgcn_sched_barrier(0);

        if (jt + 2 < nit) {
            int nb = cur + 2; if (nb >= 3) nb -= 3;
            stage(jt + 2, nb);
        }
        if (jt <= jd) {                     // qg=0 waves skip the final tile
            const __hip_bfloat16* ks = ksb + cur * 4096;
            const __hip_bfloat16* vs = vtb + cur * 4096;

            // S^T = K_slice Q^T: K A-frags loaded once, reused over 4 q-tiles
            bf16x8 ka0 = *(const bf16x8*)(ks + foK0);
            bf16x8 ka1 = *(const bf16x8*)(ks + foK1);
            f32x4 s4[4] = {};
            __builtin_amdgcn_s_setprio(1);
#pragma unroll
            for (int tq = 0; tq < 4; tq++)
                s4[tq] = __builtin_amdgcn_mfma_f32_16x16x32_bf16(
                    ka0, qf[tq][0], s4[tq], 0, 0, 0);
#pragma unroll
            for (int tq = 0; tq < 4; tq++)
                s4[tq] = __builtin_amdgcn_mfma_f32_16x16x32_bf16(
                    ka1, qf[tq][1], s4[tq], 0, 0, 0);
            __builtin_amdgcn_s_setprio(0);

            // softmax: lane holds P[q=tq*16+l16][key=kw*16+quad*4+r]
            const bool diag = (jt == jd);
            bf16x4 pa[4];
#pragma unroll
            for (int tq = 0; tq < 4; tq++) {
                float p0 = fast_exp2(s4[tq][0] * 0.1803368801f);
                float p1 = fast_exp2(s4[tq][1] * 0.1803368801f);
                float p2 = fast_exp2(s4[tq][2] * 0.1803368801f);
                float p3 = fast_exp2(s4[tq][3] * 0.1803368801f);
                if (diag) {
                    int k0 = kw * 16 + quad * 4;
                    int qq = tq * 16 + l16;
                    p0 = (k0 + 0 <= qq) ? p0 : 0.f;
                    p1 = (k0 + 1 <= qq) ? p1 : 0.f;
                    p2 = (k0 + 2 <= qq) ? p2 : 0.f;
                    p3 = (k0 + 3 <= qq) ? p3 : 0.f;
                }
                union { unsigned u[2]; bf16x4 v; } pu;
                pu.u[0] = cvt_pk_bf16(p0, p1);
                pu.u[1] = cvt_pk_bf16(p2, p3);
                pa[tq] = pu.v;              // = 16x16x16 A-frag, in-register
            }

            // PV: V B-frags loaded once (4x b64), reused over q-tiles; +ones
            bf16x4 vf0 = *(const bf16x4*)(vs + vb[0]);
            bf16x4 vf1 = *(const bf16x4*)(vs + vb[1]);
            bf16x4 vf2 = *(const bf16x4*)(vs + vb[2]);
            bf16x4 vf3 = *(const bf16x4*)(vs + vb[3]);
            __builtin_amdgcn_s_setprio(1);
#pragma unroll
            for (int tq = 0; tq < 4; tq++) {
                oacc[tq][0] = __builtin_amdgcn_mfma_f32_16x16x16bf16_1k(
                    pa[tq], vf0, oacc[tq][0], 0, 0, 0);
                oacc[tq][1] = __builtin_amdgcn_mfma_f32_16x16x16bf16_1k(
                    pa[tq], vf1, oacc[tq][1], 0, 0, 0);
                oacc[tq][2] = __builtin_amdgcn_mfma_f32_16x16x16bf16_1k(
                    pa[tq], vf2, oacc[tq][2], 0, 0, 0);
                oacc[tq][3] = __builtin_amdgcn_mfma_f32_16x16x16bf16_1k(
                    pa[tq], vf3, oacc[tq][3], 0, 0, 0);
                lacc[tq] = __builtin_amdgcn_mfma_f32_16x16x16bf16_1k(
                    pa[tq], ones4, lacc[tq], 0, 0, 0);
            }
            __builtin_amdgcn_s_setprio(0);
        }
        cur = cur + 1; if (cur >= 3) cur -= 3;
    }

    // ---- epilogue: 4-way k-slice reduction within each q-half ----
    __syncthreads();                         // all LDS tile reads done
    f32x4* const osh = (f32x4*)smem;                    // 32 KB per dt pass
    f32x4* const lsh = (f32x4*)(smem + 16384);          // 2 KB at byte 32768

    // l exchange: lanes l16==0 hold lacc[tq][r] = l_part[q=tq*16+quad*4+r]
    if (l16 == 0) {
#pragma unroll
        for (int tq = 0; tq < 4; tq++)
            lsh[((qg * 4 + kw) * 4 + tq) * 4 + quad] = lacc[tq];
    }
    __syncthreads();
    // wave (qg,kw) owns output tq == kw
    f32x4 lt = lsh[((qg * 4 + 0) * 4 + kw) * 4 + quad];  // broadcast read
#pragma unroll
    for (int src = 1; src < 4; src++)
        lt += lsh[((qg * 4 + src) * 4 + kw) * 4 + quad];
    f32x4 ilv;
#pragma unroll
    for (int r = 0; r < 4; r++) ilv[r] = 1.0f / lt[r];

    // O exchange: 4 passes (one per dt), 32 KB each
#pragma unroll
    for (int dt = 0; dt < 4; dt++) {
        __syncthreads();                     // previous pass reads done
#pragma unroll
        for (int tq = 0; tq < 4; tq++)
            osh[((qg * 4 + kw) * 4 + tq) * 64 + lane] = oacc[tq][dt];
        __syncthreads();
        f32x4 os = osh[((qg * 4 + 0) * 4 + kw) * 64 + lane];
#pragma unroll
        for (int src = 1; src < 4; src++)
            os += osh[((qg * 4 + src) * 4 + kw) * 64 + lane];
        const int dh = dt * 16 + l16;
#pragma unroll
        for (int r = 0; r < 4; r++) {
            int qg_row = qt2 * 128 + qg * 64 + kw * 16 + quad * 4 + r;
            ctx[(((size_t)b * SEQ + qg_row) * NHEADS + h) * DHEAD + dh] =
                __float2bfloat16(os[r] * ilv[r]);
        }
    }
}

// ---------------------------------------------------------------------------
extern "C" void kernel_launch(void* const* d_in, const int* in_sizes, int n_in,
                              void* d_out, int out_size, void* d_ws, size_t ws_size,
                              hipStream_t stream)
{
    const float* x      = (const float*)d_in[0];   // [2,2048,1024]
    const float* qkv_w  = (const float*)d_in[1];   // [3072,1024]
    const float* qkv_b  = (const float*)d_in[2];   // [3072]
    const float* proj_w = (const float*)d_in[3];   // [1024,1024]
    const float* proj_b = (const float*)d_in[4];   // [1024]
    float* out = (float*)d_out;                    // [2,2048,1024]

    char* w = (char*)d_ws;
    __hip_bfloat16* qkb = (__hip_bfloat16*)w;  w += (size_t)MTOT * QKSTR * 2;         // 16 MB
    __hip_bfloat16* vtg = (__hip_bfloat16*)w;  w += (size_t)MTOT * DMODEL * 2;        //  8 MB
    __hip_bfloat16* ctx = (__hip_bfloat16*)w;  w += (size_t)MTOT * DMODEL * 2;        //  8 MB
    __hip_bfloat16* xb  = (__hip_bfloat16*)w;  w += (size_t)MTOT * DMODEL * 2;        //  8 MB
    __hip_bfloat16* wqk = (__hip_bfloat16*)w;  w += (size_t)3 * DMODEL * DMODEL * 2;  //  6 MB
    __hip_bfloat16* wpr = (__hip_bfloat16*)w;                                         //  2 MB

    const int na4 = MTOT * DMODEL / 4;
    const int nb4 = 3 * DMODEL * DMODEL / 4;
    const int nc4 = DMODEL * DMODEL / 4;

    // 0) fused bf16 casts
    cast_all_kernel<<<(na4 + nb4 + nc4 + 255) / 256, 256, 0, stream>>>(
        x, xb, na4, qkv_w, wqk, nb4, proj_w, wpr, nc4);

    // 1) qkv projection: q,k (RoPE'd) -> qkb; V -> vtg (transposed), fused
    //    128x128 tiles -> 32x24 = 768 blocks = 3/CU
    gemm_bias_kernel<__hip_bfloat16, 1, 128, 128, 3>
        <<<dim3(MTOT / 128, (3 * DMODEL) / 128), 256, 0, stream>>>(
        xb, wqk, qkv_b, qkb, vtg, MTOT, 3 * DMODEL, DMODEL);

    // 2) causal MFMA flash attention -> ctx [B,S,H,Dh] bf16
    //    512 blocks of 512 thr (QBLK=128), 48KB LDS, LPT longest-first
    flash_attn_mfma_kernel<<<512, 512, 0, stream>>>(qkb, vtg, ctx);

    // 3) out = ctx @ proj_w^T + proj_b -> fp32 d_out
    //    64x128 tiles -> 64x8 = 512 blocks = 2/CU
    gemm_bias_kernel<float, 0, 64, 128, 6>
        <<<dim3(MTOT / 64, DMODEL / 128), 256, 0, stream>>>(
        ctx, wpr, proj_b, out, nullptr, MTOT, DMODEL, DMODEL);
}